// Round 3
// baseline (121.932 us; speedup 1.0000x reference)
//
#include <hip/hip_runtime.h>

namespace {
constexpr int CH = 128, HH = 56, WW = 56;
constexpr int R  = 2;    // h rows per block
constexpr int LP = 60;   // padded l-dim: [2 zeros][56][2 zeros]

__global__ __launch_bounds__(256, 6) void fused_conv_kernel(
    const float* __restrict__ x,
    const float* __restrict__ w0,
    const float* __restrict__ w1,
    float* __restrict__ out)
{
    __shared__ float t4s[R][2][4][LP];   // [r][m][i][lpad]
    __shared__ float w0s[2 * 3 * 3 * 32];

    const int tid = threadIdx.x;
    const int b   = blockIdx.x / (HH / R);
    const int hg  = blockIdx.x - b * (HH / R);
    const int h0  = hg * R;

    // stage weights (tiny)
    for (int t = tid; t < 576; t += 256) w0s[t] = w0[t];

    // zero ONLY the pad columns (padded idx 0,1,58,59); disjoint from stage-1
    // writes (which cover padded idx 2..57)
    if (tid < R * 32) {
        int e = tid;
        const int r = e >> 5; e &= 31;
        const int m = e >> 4; e &= 15;
        const int i = e >> 2;
        const int p = e & 3;
        t4s[r][m][i][(p < 2) ? p : (56 + p)] = 0.f;
    }

    // stage 1: channel mix straight from global (each x element read once).
    // item = r*112 + m*56 + l  -> lanes contiguous in l => coalesced loads.
    if (tid < R * 112) {
        int e = tid;
        const int r = e / 112; e -= r * 112;
        const int m = e / 56;
        const int l = e - m * 56;
        const float*  xp  = x + (((size_t)b * CH + m) * HH + (h0 + r)) * WW + l;
        const float4* w1v = (const float4*)w1;   // w1[j][0..3], lane-uniform
        float a0 = 0.f, a1 = 0.f, a2 = 0.f, a3 = 0.f;
        #pragma unroll 8
        for (int j = 0; j < 64; ++j) {
            const float  xv = xp[(size_t)j * (2 * HH * WW)];
            const float4 wv = w1v[j];
            a0 = fmaf(xv, wv.x, a0);
            a1 = fmaf(xv, wv.y, a1);
            a2 = fmaf(xv, wv.z, a2);
            a3 = fmaf(xv, wv.w, a3);
        }
        t4s[r][m][0][2 + l] = a0;
        t4s[r][m][1][2 + l] = a1;
        t4s[r][m][2][2 + l] = a2;
        t4s[r][m][3][2 + l] = a3;
    }
    __syncthreads();

    // stage 2: 9-tap conv along l + boundary fixups; 4 w per thread-item.
    #pragma unroll 2
    for (int it = 0; it < R * 7; ++it) {
        const int t  = it * 256 + tid;
        const int r  = t / 1792;
        const int tt = t - r * 1792;
        const int c  = tt / 14;          // output channel = j*4+i
        const int q  = tt - c * 14;
        const int l0 = q * 4;
        const int j  = c >> 2;
        const int i  = c & 3;

        // padded window t4[m][i][l0-2 .. l0+5] as aligned float4 pairs
        const float* tp0 = &t4s[r][0][i][l0];
        const float* tp1 = &t4s[r][1][i][l0];
        const float4 p0a = *(const float4*)(tp0);
        const float4 p0b = *(const float4*)(tp0 + 4);
        const float4 p1a = *(const float4*)(tp1);
        const float4 p1b = *(const float4*)(tp1 + 4);
        const float v0[8] = {p0a.x, p0a.y, p0a.z, p0a.w, p0b.x, p0b.y, p0b.z, p0b.w};
        const float v1[8] = {p1a.x, p1a.y, p1a.z, p1a.w, p1b.x, p1b.y, p1b.z, p1b.w};

        float acc0 = 0.f, acc1 = 0.f, acc2 = 0.f, acc3 = 0.f;
        #pragma unroll
        for (int m = 0; m < 2; ++m) {
            #pragma unroll
            for (int kB = 0; kB < 3; ++kB) {
                #pragma unroll
                for (int kA = 0; kA < 3; ++kA) {
                    const float wv = w0s[((m * 3 + kB) * 3 + kA) * 32 + j];
                    const int dd = kA + kB;            // compile-time after unroll
                    acc0 = fmaf(m ? v1[dd]     : v0[dd],     wv, acc0);
                    acc1 = fmaf(m ? v1[dd + 1] : v0[dd + 1], wv, acc1);
                    acc2 = fmaf(m ? v1[dd + 2] : v0[dd + 2], wv, acc2);
                    acc3 = fmaf(m ? v1[dd + 3] : v0[dd + 3], wv, acc3);
                }
            }
        }

        // boundary fixups: kB=0 invalid at w=0; kB=2 invalid at w=55
        if (l0 == 0) {
            #pragma unroll
            for (int m = 0; m < 2; ++m)
                acc0 -= t4s[r][m][i][2] * w0s[((m * 3 + 0) * 3 + 2) * 32 + j];
        }
        if (l0 == 52) {
            #pragma unroll
            for (int m = 0; m < 2; ++m)
                acc3 -= t4s[r][m][i][57] * w0s[((m * 3 + 2) * 3 + 0) * 32 + j];
        }

        const int h_out = (h0 + r + 1) % HH;    // roll(+1) along H
        float* orow = out + (((size_t)b * CH + c) * HH + h_out) * WW + l0;
        *(float4*)orow = make_float4(acc0, acc1, acc2, acc3);
    }
}
} // namespace

extern "C" void kernel_launch(void* const* d_in, const int* in_sizes, int n_in,
                              void* d_out, int out_size, void* d_ws, size_t ws_size,
                              hipStream_t stream) {
    const float* x  = (const float*)d_in[0];
    const float* w0 = (const float*)d_in[1];
    const float* w1 = (const float*)d_in[2];
    float* out = (float*)d_out;
    fused_conv_kernel<<<dim3(128 * (HH / R)), dim3(256), 0, stream>>>(x, w0, w1, out);
}